// Round 1
// baseline (299.328 us; speedup 1.0000x reference)
//
#include <hip/hip_runtime.h>
#include <math.h>

// CandidateAwareClock: per row b
//   q = emb[cand[b]]; k_l = emb[items[b,l]]
//   logits_l = dot(k_l,q) * gate[dts[b,l]] / tau   (gate row 0 == 0)
//   masked softmax over l -> attn; u = sum_l attn_l * k_l
//   tau = softplus(raw_tau) + 1e-6
// Outputs concatenated: u [B*64], attn [B*200], tau [1]

constexpr int Bsz  = 4096;
constexpr int Lseq = 200;
constexpr int Dim  = 64;

__global__ __launch_bounds__(256, 2)
void cac_kernel(const int* __restrict__ items,
                const int* __restrict__ dts,
                const int* __restrict__ mask,
                const int* __restrict__ cand,
                const float* __restrict__ emb,
                const float* __restrict__ gate,
                const float* __restrict__ rawtau,
                float* __restrict__ out_u,
                float* __restrict__ out_attn,
                float* __restrict__ out_tau)
{
    __shared__ float k_lds[Lseq][Dim];   // 51.2 KB staged gather
    __shared__ float sc_lds[Lseq];       // sim, then attn
    __shared__ float red[8];
    __shared__ float part[4][Dim];

    const int b    = blockIdx.x;
    const int tid  = threadIdx.x;
    const int wave = tid >> 6;
    const int lane = tid & 63;

    // tau (cheap, every block computes; block 0 writes)
    const float raw = rawtau[0];
    const float sp  = (raw > 20.f) ? raw : log1pf(expf(raw));
    const float tau = sp + 1e-6f;
    const float inv_tau = 1.0f / tau;
    if (b == 0 && tid == 0) out_tau[0] = tau;

    // q fragment: lane d holds q[d]
    const float qd = emb[cand[b] * Dim + lane];

    // ---- Phase 1: gather k rows (coalesced 256B/row), sim via wave reduce ----
    for (int l = wave; l < Lseq; l += 4) {
        const int row = items[b * Lseq + l];          // wave-uniform -> s_load
        const float kv = emb[row * Dim + lane];
        k_lds[l][lane] = kv;
        float p = kv * qd;
        #pragma unroll
        for (int off = 32; off > 0; off >>= 1)
            p += __shfl_xor(p, off, 64);
        if (lane == 0) sc_lds[l] = p;
    }
    __syncthreads();

    // ---- Phase 2: gated masked softmax over L ----
    float logit = -INFINITY;
    if (tid < Lseq) {
        const int dt = dts[b * Lseq + tid];
        const float g = (dt == 0) ? 0.f : gate[dt];   // padding_idx=0
        const int m  = mask[b * Lseq + tid];
        logit = m ? (sc_lds[tid] * g * inv_tau) : -INFINITY;
    }
    float v = logit;
    #pragma unroll
    for (int off = 32; off > 0; off >>= 1)
        v = fmaxf(v, __shfl_xor(v, off, 64));
    if (lane == 0) red[wave] = v;
    __syncthreads();
    const float mx = fmaxf(fmaxf(red[0], red[1]), fmaxf(red[2], red[3]));

    float e = (tid < Lseq) ? expf(logit - mx) : 0.f;  // exp(-inf)=0 for masked
    v = e;
    #pragma unroll
    for (int off = 32; off > 0; off >>= 1)
        v += __shfl_xor(v, off, 64);
    if (lane == 0) red[4 + wave] = v;                 // disjoint slots: no extra sync needed
    __syncthreads();
    const float inv_s = 1.0f / (red[4] + red[5] + red[6] + red[7]);

    if (tid < Lseq) {
        const float a = e * inv_s;
        sc_lds[tid] = a;
        out_attn[b * Lseq + tid] = a;
    }
    __syncthreads();

    // ---- Phase 3: u[d] = sum_l attn[l] * k[l][d] ----
    float acc = 0.f;
    for (int l = wave; l < Lseq; l += 4)
        acc = fmaf(sc_lds[l], k_lds[l][lane], acc);   // sc_lds broadcast, k_lds 2-way (free)
    part[wave][lane] = acc;
    __syncthreads();
    if (wave == 0)
        out_u[b * Dim + lane] = part[0][lane] + part[1][lane] + part[2][lane] + part[3][lane];
}

extern "C" void kernel_launch(void* const* d_in, const int* in_sizes, int n_in,
                              void* d_out, int out_size, void* d_ws, size_t ws_size,
                              hipStream_t stream) {
    const int*   items  = (const int*)  d_in[0];  // [B,L]
    const int*   dts    = (const int*)  d_in[1];  // [B,L]
    const int*   mask   = (const int*)  d_in[2];  // [B,L] bool as int
    const int*   cand   = (const int*)  d_in[3];  // [B]
    const float* emb    = (const float*)d_in[4];  // [VOCAB,64]
    const float* gate   = (const float*)d_in[5];  // [128,1]
    const float* rawtau = (const float*)d_in[6];  // [1]

    float* out_u    = (float*)d_out;                       // B*64
    float* out_attn = out_u + Bsz * Dim;                   // B*200
    float* out_tau  = out_attn + Bsz * Lseq;               // 1

    cac_kernel<<<Bsz, 256, 0, stream>>>(items, dts, mask, cand, emb, gate, rawtau,
                                        out_u, out_attn, out_tau);
}

// Round 3
// 169.004 us; speedup vs baseline: 1.7711x; 1.7711x over previous
//
#include <hip/hip_runtime.h>
#include <math.h>

// CandidateAwareClock: per row b
//   q = emb[cand[b]]; k_l = emb[items[b,l]]
//   logits_l = dot(k_l,q) * gate[dts[b,l]] / tau   (gate row 0 == 0)
//   masked softmax over l -> attn; u = sum_l attn_l * k_l
//   tau = softplus(raw_tau) + 1e-6
// Outputs concatenated: u [B*64], attn [B*200], tau [1]
//
// R3: coalesced row gather (64 lanes = one 256B row) like R1, but:
//  - no k_lds staging (emb is L2/L3-resident; re-gather in phase 3)
//  - mask-skip: masked rows (wave-uniform condition) skip the gather entirely,
//    zero-attn rows skip the phase-3 gather  (~2x traffic cut)
//  - 2-row unroll in phase 1: two independent load->shuffle chains per wave
//  - LDS ~3.4KB; __launch_bounds__(256,8) targets VGPR<=64 -> 32 waves/CU

constexpr int Bsz  = 4096;
constexpr int Lseq = 200;
constexpr int Dim  = 64;

__global__ __launch_bounds__(256, 8)
void cac_kernel(const int* __restrict__ items,
                const int* __restrict__ dts,
                const int* __restrict__ mask,
                const int* __restrict__ cand,
                const float* __restrict__ emb,
                const float* __restrict__ gate,
                const float* __restrict__ rawtau,
                float* __restrict__ out_u,
                float* __restrict__ out_attn,
                float* __restrict__ out_tau)
{
    __shared__ int   rows_lds[Lseq];
    __shared__ int   msk_lds[Lseq];
    __shared__ float sc_lds[Lseq];      // sim, then attn
    __shared__ float redmax[4];
    __shared__ float redsum[4];
    __shared__ float part[4][Dim];

    const int b    = blockIdx.x;
    const int tid  = threadIdx.x;
    const int wave = tid >> 6;
    const int lane = tid & 63;

    // tau
    const float raw = rawtau[0];
    const float sp  = (raw > 20.f) ? raw : log1pf(expf(raw));
    const float tau = sp + 1e-6f;
    const float inv_tau = 1.0f / tau;
    if (b == 0 && tid == 0) out_tau[0] = tau;

    // q fragment: lane d holds q[d] (coalesced 256B read)
    const float qd = emb[(size_t)cand[b] * Dim + lane];

    // stage indices + mask (coalesced int loads)
    if (tid < Lseq) {
        rows_lds[tid] = items[b * Lseq + tid];
        msk_lds[tid]  = mask[b * Lseq + tid];
    }
    __syncthreads();

    // ---- Phase 1: coalesced gather + paired wave reduce; skip masked rows ----
    // l covers {wave + 8k} u {wave+4 + 8k}; all waves together cover 0..199.
    for (int l = wave; l < Lseq; l += 8) {
        const int l1 = l + 4;
        float p0 = 0.f, p1 = 0.f;
        if (msk_lds[l])                       // wave-uniform -> execz skip
            p0 = emb[(size_t)rows_lds[l]  * Dim + lane] * qd;
        if (msk_lds[l1])
            p1 = emb[(size_t)rows_lds[l1] * Dim + lane] * qd;
        #pragma unroll
        for (int off = 32; off > 0; off >>= 1) {
            p0 += __shfl_xor(p0, off, 64);
            p1 += __shfl_xor(p1, off, 64);
        }
        if (lane == 0) { sc_lds[l] = p0; sc_lds[l1] = p1; }   // masked rows get 0
    }
    __syncthreads();

    // ---- Phase 2: gated masked softmax over L ----
    float logit = -INFINITY;
    if (tid < Lseq) {
        const int   dt = dts[b * Lseq + tid];
        const float g  = (dt == 0) ? 0.f : gate[dt];   // padding_idx=0
        logit = msk_lds[tid] ? (sc_lds[tid] * g * inv_tau) : -INFINITY;
    }
    float v = logit;
    #pragma unroll
    for (int off = 32; off > 0; off >>= 1)
        v = fmaxf(v, __shfl_xor(v, off, 64));
    if (lane == 0) redmax[wave] = v;
    __syncthreads();
    const float mx = fmaxf(fmaxf(redmax[0], redmax[1]), fmaxf(redmax[2], redmax[3]));

    const float e = (tid < Lseq) ? expf(logit - mx) : 0.f;   // exp(-inf)=0 masked
    v = e;
    #pragma unroll
    for (int off = 32; off > 0; off >>= 1)
        v += __shfl_xor(v, off, 64);
    if (lane == 0) redsum[wave] = v;
    __syncthreads();
    const float inv_s = 1.0f / (redsum[0] + redsum[1] + redsum[2] + redsum[3]);

    if (tid < Lseq) {
        const float a = e * inv_s;
        sc_lds[tid] = a;                      // overwrite sim with attn (barriers above/below)
        out_attn[b * Lseq + tid] = a;
    }
    __syncthreads();

    // ---- Phase 3: u[d] = sum_l attn[l]*emb[row_l][d]; skip zero-attn rows ----
    float acc = 0.f;
    for (int l = wave; l < Lseq; l += 8) {
        const int l1 = l + 4;
        const float a0 = sc_lds[l];           // wave-uniform LDS broadcast
        const float a1 = sc_lds[l1];
        if (a0 != 0.f)
            acc = fmaf(a0, emb[(size_t)rows_lds[l]  * Dim + lane], acc);
        if (a1 != 0.f)
            acc = fmaf(a1, emb[(size_t)rows_lds[l1] * Dim + lane], acc);
    }
    part[wave][lane] = acc;
    __syncthreads();
    if (wave == 0)
        out_u[b * Dim + lane] = (part[0][lane] + part[1][lane])
                              + (part[2][lane] + part[3][lane]);
}

extern "C" void kernel_launch(void* const* d_in, const int* in_sizes, int n_in,
                              void* d_out, int out_size, void* d_ws, size_t ws_size,
                              hipStream_t stream) {
    const int*   items  = (const int*)  d_in[0];  // [B,L]
    const int*   dts    = (const int*)  d_in[1];  // [B,L]
    const int*   mask   = (const int*)  d_in[2];  // [B,L]
    const int*   cand   = (const int*)  d_in[3];  // [B]
    const float* emb    = (const float*)d_in[4];  // [VOCAB,64]
    const float* gate   = (const float*)d_in[5];  // [128,1]
    const float* rawtau = (const float*)d_in[6];  // [1]

    float* out_u    = (float*)d_out;                       // B*64
    float* out_attn = out_u + Bsz * Dim;                   // B*200
    float* out_tau  = out_attn + Bsz * Lseq;               // 1

    cac_kernel<<<Bsz, 256, 0, stream>>>(items, dts, mask, cand, emb, gate, rawtau,
                                        out_u, out_attn, out_tau);
}

// Round 5
// 134.105 us; speedup vs baseline: 2.2320x; 1.2602x over previous
//
#include <hip/hip_runtime.h>
#include <math.h>

// CandidateAwareClock: per row b
//   q = emb[cand[b]]; k_l = emb[items[b,l]]
//   logits_l = dot(k_l,q) * gate[dts[b,l]] / tau   (gate row 0 == 0)
//   masked softmax over l -> attn; u = sum_l attn_l * k_l
//   tau = softplus(raw_tau) + 1e-6
// Outputs concatenated: u [B*64], attn [B*200], tau [1]
//
// R4 (resubmit after infra timeout): phase 1 uses 4 lanes per row
// (lane = 4r+j): each lane loads 4x float4 (64B = one aligned cache line)
// of its row, dots vs q (LDS), reduces across 4 lanes (2 shuffle steps).
// Per 16 rows: 4 wide loads + 2 shuffles vs 16 loads + 96 swizzles in R3.
// No exec-branching in the gather loop -> compiler pipelines all loads.
// Phase 3 keeps coalesced gather + zero-attn skip.

constexpr int Bsz  = 4096;
constexpr int Lseq = 200;
constexpr int Dim  = 64;
constexpr int NGRP = (Lseq + 15) / 16;   // 13 groups of 16 rows

__global__ __launch_bounds__(256, 8)
void cac_kernel(const int* __restrict__ items,
                const int* __restrict__ dts,
                const int* __restrict__ mask,
                const int* __restrict__ cand,
                const float* __restrict__ emb,
                const float* __restrict__ gate,
                const float* __restrict__ rawtau,
                float* __restrict__ out_u,
                float* __restrict__ out_attn,
                float* __restrict__ out_tau)
{
    __shared__ __align__(16) float q_lds[Dim];
    __shared__ int   rows_lds[Lseq];
    __shared__ float sc_lds[Lseq];      // sim, then attn
    __shared__ float redmax[4];
    __shared__ float redsum[4];
    __shared__ float part[4][Dim];

    const int b    = blockIdx.x;
    const int tid  = threadIdx.x;
    const int wave = tid >> 6;
    const int lane = tid & 63;

    // tau
    const float raw = rawtau[0];
    const float sp  = (raw > 20.f) ? raw : log1pf(expf(raw));
    const float tau = sp + 1e-6f;
    const float inv_tau = 1.0f / tau;
    if (b == 0 && tid == 0) out_tau[0] = tau;

    // stage q (64 floats) + row indices (coalesced)
    if (tid < Dim) q_lds[tid] = emb[(size_t)cand[b] * Dim + tid];
    if (tid < Lseq) rows_lds[tid] = items[b * Lseq + tid];
    __syncthreads();

    // ---- Phase 1: 4 lanes per row; 16 rows per wave-instruction ----
    const int r = lane >> 2;            // row within group (0..15)
    const int j = lane & 3;             // 64B chunk within row (0..3)
    const float4* q4 = (const float4*)q_lds;
    for (int g = wave; g < NGRP; g += 4) {
        const int  l     = g * 16 + r;
        const bool valid = (l < Lseq);
        const int  lc    = valid ? l : (Lseq - 1);
        const int  row   = rows_lds[lc];
        const float4* kp = (const float4*)(emb + (size_t)row * Dim);
        float a0 = 0.f, a1 = 0.f, a2 = 0.f, a3 = 0.f;
        #pragma unroll
        for (int i = 0; i < 4; ++i) {
            const float4 kv = kp[i * 4 + j];     // 16B, lane's 64B line
            const float4 qv = q4[i * 4 + j];     // LDS, 4-addr broadcast
            a0 = fmaf(kv.x, qv.x, a0);
            a1 = fmaf(kv.y, qv.y, a1);
            a2 = fmaf(kv.z, qv.z, a2);
            a3 = fmaf(kv.w, qv.w, a3);
        }
        float p = (a0 + a1) + (a2 + a3);
        p += __shfl_xor(p, 1, 64);               // sum over j (4 lanes)
        p += __shfl_xor(p, 2, 64);
        if (valid && j == 0) sc_lds[l] = p;
    }
    __syncthreads();

    // ---- Phase 2: gated masked softmax over L ----
    float logit = -INFINITY;
    if (tid < Lseq) {
        const int   dt = dts[b * Lseq + tid];
        const float g  = (dt == 0) ? 0.f : gate[dt];   // padding_idx=0
        logit = mask[b * Lseq + tid] ? (sc_lds[tid] * g * inv_tau) : -INFINITY;
    }
    float v = logit;
    #pragma unroll
    for (int off = 32; off > 0; off >>= 1)
        v = fmaxf(v, __shfl_xor(v, off, 64));
    if (lane == 0) redmax[wave] = v;
    __syncthreads();
    const float mx = fmaxf(fmaxf(redmax[0], redmax[1]), fmaxf(redmax[2], redmax[3]));

    const float e = (tid < Lseq) ? expf(logit - mx) : 0.f;   // exp(-inf)=0 masked
    v = e;
    #pragma unroll
    for (int off = 32; off > 0; off >>= 1)
        v += __shfl_xor(v, off, 64);
    if (lane == 0) redsum[wave] = v;
    __syncthreads();
    const float inv_s = 1.0f / (redsum[0] + redsum[1] + redsum[2] + redsum[3]);

    if (tid < Lseq) {
        const float a = e * inv_s;
        sc_lds[tid] = a;                  // overwrite sim with attn (barrier above/below)
        out_attn[b * Lseq + tid] = a;
    }
    __syncthreads();

    // ---- Phase 3: u[d] = sum_l attn[l]*emb[row_l][d]; skip zero-attn rows ----
    float acc = 0.f;
    for (int l = wave; l < Lseq; l += 8) {
        const int l1 = l + 4;
        const float a0 = sc_lds[l];       // wave-uniform LDS broadcast
        const float a1 = sc_lds[l1];
        if (a0 != 0.f)
            acc = fmaf(a0, emb[(size_t)rows_lds[l]  * Dim + lane], acc);
        if (a1 != 0.f)
            acc = fmaf(a1, emb[(size_t)rows_lds[l1] * Dim + lane], acc);
    }
    part[wave][lane] = acc;
    __syncthreads();
    if (wave == 0)
        out_u[b * Dim + lane] = (part[0][lane] + part[1][lane])
                              + (part[2][lane] + part[3][lane]);
}

extern "C" void kernel_launch(void* const* d_in, const int* in_sizes, int n_in,
                              void* d_out, int out_size, void* d_ws, size_t ws_size,
                              hipStream_t stream) {
    const int*   items  = (const int*)  d_in[0];  // [B,L]
    const int*   dts    = (const int*)  d_in[1];  // [B,L]
    const int*   mask   = (const int*)  d_in[2];  // [B,L]
    const int*   cand   = (const int*)  d_in[3];  // [B]
    const float* emb    = (const float*)d_in[4];  // [VOCAB,64]
    const float* gate   = (const float*)d_in[5];  // [128,1]
    const float* rawtau = (const float*)d_in[6];  // [1]

    float* out_u    = (float*)d_out;                       // B*64
    float* out_attn = out_u + Bsz * Dim;                   // B*200
    float* out_tau  = out_attn + Bsz * Lseq;               // 1

    cac_kernel<<<Bsz, 256, 0, stream>>>(items, dts, mask, cand, emb, gate, rawtau,
                                        out_u, out_attn, out_tau);
}

// Round 7
// 121.531 us; speedup vs baseline: 2.4630x; 1.1035x over previous
//
#include <hip/hip_runtime.h>
#include <math.h>

// CandidateAwareClock: per row b
//   q = emb[cand[b]]; k_l = emb[items[b,l]]
//   logits_l = dot(k_l,q) * gate[dts[b,l]] / tau   (gate row 0 == 0)
//   masked softmax over l -> attn; u = sum_l attn_l * k_l
//   tau = softplus(raw_tau) + 1e-6
// Outputs concatenated: u [B*64], attn [B*200], tau [1]
//
// R5 (resubmit after infra timeout): ballot-compaction of valid (mask!=0)
// positions; both gather phases run branch-free over the compacted list
// (~50% fewer gathers in phase 1, no exec-mask branches in phase 3).
// __launch_bounds__(256,4) relaxes VGPR cap (R4's 24 VGPRs left only ~2-3
// loads in flight; we want 8+).

constexpr int Bsz  = 4096;
constexpr int Lseq = 200;
constexpr int Dim  = 64;

__global__ __launch_bounds__(256, 4)
void cac_kernel(const int* __restrict__ items,
                const int* __restrict__ dts,
                const int* __restrict__ mask,
                const int* __restrict__ cand,
                const float* __restrict__ emb,
                const float* __restrict__ gate,
                const float* __restrict__ rawtau,
                float* __restrict__ out_u,
                float* __restrict__ out_attn,
                float* __restrict__ out_tau)
{
    __shared__ __align__(16) float q_lds[Dim];
    __shared__ int   rows_lds[Lseq];    // item id per original position
    __shared__ float sc_lds[Lseq];      // sim, then attn (by original position)
    __shared__ int   comp_lds[Lseq];    // compacted valid positions
    __shared__ int   wcnt[4];
    __shared__ float redmax[4];
    __shared__ float redsum[4];
    __shared__ float part[4][Dim];

    const int b    = blockIdx.x;
    const int tid  = threadIdx.x;
    const int wave = tid >> 6;
    const int lane = tid & 63;

    // tau
    const float raw = rawtau[0];
    const float sp  = (raw > 20.f) ? raw : log1pf(expf(raw));
    const float tau = sp + 1e-6f;
    const float inv_tau = 1.0f / tau;
    if (b == 0 && tid == 0) out_tau[0] = tau;

    // stage q + indices; read mask into register
    if (tid < Dim) q_lds[tid] = emb[(size_t)cand[b] * Dim + tid];
    int m = 0;
    if (tid < Lseq) {
        rows_lds[tid] = items[b * Lseq + tid];
        m = mask[b * Lseq + tid];
    }

    // ---- ballot compaction of valid positions ----
    const unsigned long long bal = __ballot(m != 0);
    if (lane == 0) wcnt[wave] = __popcll(bal);
    __syncthreads();
    int base = 0;
    #pragma unroll
    for (int w = 0; w < 4; ++w) if (w < wave) base += wcnt[w];
    const int cnt = wcnt[0] + wcnt[1] + wcnt[2] + wcnt[3];
    if (m) {
        const int prefix = __popcll(bal & ((1ull << lane) - 1ull));
        comp_lds[base + prefix] = tid;
    }
    __syncthreads();

    // ---- Phase 1: 4 lanes per compacted entry; 16 entries per group ----
    const int r = lane >> 2;            // entry within group (0..15)
    const int j = lane & 3;             // 64B chunk within row (0..3)
    const float4* q4 = (const float4*)q_lds;
    const int ngrp = (cnt + 15) >> 4;
    for (int g = wave; g < ngrp; g += 4) {
        const int  e     = g * 16 + r;
        const bool valid = (e < cnt);
        const int  ec    = valid ? e : (cnt - 1);
        const int  l     = comp_lds[ec];
        const int  row   = rows_lds[l];
        const float4* kp = (const float4*)(emb + (size_t)row * Dim);
        float a0 = 0.f, a1 = 0.f, a2 = 0.f, a3 = 0.f;
        #pragma unroll
        for (int i = 0; i < 4; ++i) {
            const float4 kv = kp[i * 4 + j];     // lane's 64B line of the row
            const float4 qv = q4[i * 4 + j];     // LDS broadcast
            a0 = fmaf(kv.x, qv.x, a0);
            a1 = fmaf(kv.y, qv.y, a1);
            a2 = fmaf(kv.z, qv.z, a2);
            a3 = fmaf(kv.w, qv.w, a3);
        }
        float p = (a0 + a1) + (a2 + a3);
        p += __shfl_xor(p, 1, 64);               // reduce over j (4 lanes)
        p += __shfl_xor(p, 2, 64);
        if (valid && j == 0) sc_lds[l] = p;
    }
    __syncthreads();

    // ---- Phase 2: gated masked softmax over all 200 positions ----
    float logit = -INFINITY;
    if (tid < Lseq) {
        const int   dt = dts[b * Lseq + tid];
        const float g  = (dt == 0) ? 0.f : gate[dt];   // padding_idx=0
        logit = m ? (sc_lds[tid] * g * inv_tau) : -INFINITY;
    }
    float v = logit;
    #pragma unroll
    for (int off = 32; off > 0; off >>= 1)
        v = fmaxf(v, __shfl_xor(v, off, 64));
    if (lane == 0) redmax[wave] = v;
    __syncthreads();
    const float mx = fmaxf(fmaxf(redmax[0], redmax[1]), fmaxf(redmax[2], redmax[3]));

    const float e_ = (tid < Lseq) ? expf(logit - mx) : 0.f;  // exp(-inf)=0 masked
    v = e_;
    #pragma unroll
    for (int off = 32; off > 0; off >>= 1)
        v += __shfl_xor(v, off, 64);
    if (lane == 0) redsum[wave] = v;
    __syncthreads();
    const float inv_s = 1.0f / (redsum[0] + redsum[1] + redsum[2] + redsum[3]);

    if (tid < Lseq) {
        const float a = e_ * inv_s;
        sc_lds[tid] = a;                  // overwrite sim with attn (barriers around)
        out_attn[b * Lseq + tid] = a;
    }
    __syncthreads();

    // ---- Phase 3: coalesced gather over compacted entries (branch-free) ----
    float acc = 0.f;
    for (int e = wave; e < cnt; e += 8) {         // 2 entries/iter, wave-uniform
        const int   l0 = comp_lds[e];
        const float a0 = sc_lds[l0];
        acc = fmaf(a0, emb[(size_t)rows_lds[l0] * Dim + lane], acc);
        const int e1 = e + 4;
        if (e1 < cnt) {                           // wave-uniform scalar branch
            const int l1 = comp_lds[e1];
            acc = fmaf(sc_lds[l1], emb[(size_t)rows_lds[l1] * Dim + lane], acc);
        }
    }
    part[wave][lane] = acc;
    __syncthreads();
    if (wave == 0)
        out_u[b * Dim + lane] = (part[0][lane] + part[1][lane])
                              + (part[2][lane] + part[3][lane]);
}

extern "C" void kernel_launch(void* const* d_in, const int* in_sizes, int n_in,
                              void* d_out, int out_size, void* d_ws, size_t ws_size,
                              hipStream_t stream) {
    const int*   items  = (const int*)  d_in[0];  // [B,L]
    const int*   dts    = (const int*)  d_in[1];  // [B,L]
    const int*   mask   = (const int*)  d_in[2];  // [B,L]
    const int*   cand   = (const int*)  d_in[3];  // [B]
    const float* emb    = (const float*)d_in[4];  // [VOCAB,64]
    const float* gate   = (const float*)d_in[5];  // [128,1]
    const float* rawtau = (const float*)d_in[6];  // [1]

    float* out_u    = (float*)d_out;                       // B*64
    float* out_attn = out_u + Bsz * Dim;                   // B*200
    float* out_tau  = out_attn + Bsz * Lseq;               // 1

    cac_kernel<<<Bsz, 256, 0, stream>>>(items, dts, mask, cand, emb, gate, rawtau,
                                        out_u, out_attn, out_tau);
}

// Round 8
// 111.643 us; speedup vs baseline: 2.6811x; 1.0886x over previous
//
#include <hip/hip_runtime.h>
#include <math.h>

// CandidateAwareClock: per row b
//   q = emb[cand[b]]; k_l = emb[items[b,l]]
//   logits_l = dot(k_l,q) * gate[dts[b,l]] / tau   (gate row 0 == 0)
//   masked softmax over l -> attn; u = sum_l attn_l * k_l
//   tau = softplus(raw_tau) + 1e-6
// Outputs concatenated: u [B*64], attn [B*200], tau [1]
//
// R8: compacted list padded to multiple of 32 (padding: row=0, attn=0) ->
// both gather phases are branch-free with uniform trip counts. Phase 3 is
// hand-pipelined: batches of 8 independent loads then 8 FMAs (static idx,
// fully unrolled). Compaction stores row (crow) and attn (cattn) directly,
// removing the position indirection from phase 3's address chain.

constexpr int Bsz  = 4096;
constexpr int Lseq = 200;
constexpr int Dim  = 64;
constexpr int CMAX = 224;            // (200+31)&~31

__global__ __launch_bounds__(256, 4)
void cac_kernel(const int* __restrict__ items,
                const int* __restrict__ dts,
                const int* __restrict__ mask,
                const int* __restrict__ cand,
                const float* __restrict__ emb,
                const float* __restrict__ gate,
                const float* __restrict__ rawtau,
                float* __restrict__ out_u,
                float* __restrict__ out_attn,
                float* __restrict__ out_tau)
{
    __shared__ __align__(16) float q_lds[Dim];
    __shared__ float sc_lds[Lseq + 1];   // sim by position (+1 dummy slot)
    __shared__ int   comp_lds[CMAX];     // compacted -> position (pad: Lseq)
    __shared__ int   crow_lds[CMAX];     // compacted -> row id   (pad: 0)
    __shared__ float cattn_lds[CMAX];    // compacted -> attn     (pad: 0)
    __shared__ int   wcnt[4];
    __shared__ float redmax[4];
    __shared__ float redsum[4];
    __shared__ float part[4][Dim];

    const int b    = blockIdx.x;
    const int tid  = threadIdx.x;
    const int wave = tid >> 6;
    const int lane = tid & 63;

    // tau
    const float raw = rawtau[0];
    const float sp  = (raw > 20.f) ? raw : log1pf(expf(raw));
    const float tau = sp + 1e-6f;
    const float inv_tau = 1.0f / tau;
    if (b == 0 && tid == 0) out_tau[0] = tau;

    // stage q; read row + mask into registers
    if (tid < Dim) q_lds[tid] = emb[(size_t)cand[b] * Dim + tid];
    int m = 0, myrow = 0;
    if (tid < Lseq) {
        myrow = items[b * Lseq + tid];
        m     = mask[b * Lseq + tid];
    }

    // ---- ballot compaction (position, row), padded to multiple of 32 ----
    const unsigned long long bal = __ballot(m != 0);
    if (lane == 0) wcnt[wave] = __popcll(bal);
    __syncthreads();
    int base = 0;
    #pragma unroll
    for (int w = 0; w < 4; ++w) if (w < wave) base += wcnt[w];
    const int cnt  = wcnt[0] + wcnt[1] + wcnt[2] + wcnt[3];
    const int cntp = (cnt + 31) & ~31;
    const int cidx = base + __popcll(bal & ((1ull << lane) - 1ull));
    if (m) {
        comp_lds[cidx] = tid;
        crow_lds[cidx] = myrow;
    }
    if (tid < cntp - cnt) {              // ≤31 padding entries
        comp_lds[cnt + tid]  = Lseq;     // dummy position slot
        crow_lds[cnt + tid]  = 0;        // any valid row
        cattn_lds[cnt + tid] = 0.f;      // zero weight
    }
    __syncthreads();

    // ---- Phase 1: 4 lanes per entry, 16 entries/group, branch-free ----
    const int r = lane >> 2;             // entry within group (0..15)
    const int j = lane & 3;              // 64B chunk within row (0..3)
    const float4* q4 = (const float4*)q_lds;
    const int ngrp = cntp >> 4;
    for (int g = wave; g < ngrp; g += 4) {
        const int e   = g * 16 + r;
        const int l   = comp_lds[e];     // 16 banks, 4-way same-addr: free
        const int row = crow_lds[e];
        const float4* kp = (const float4*)(emb + (size_t)row * Dim);
        float a0 = 0.f, a1 = 0.f, a2 = 0.f, a3 = 0.f;
        #pragma unroll
        for (int i = 0; i < 4; ++i) {
            const float4 kv = kp[i * 4 + j];
            const float4 qv = q4[i * 4 + j];
            a0 = fmaf(kv.x, qv.x, a0);
            a1 = fmaf(kv.y, qv.y, a1);
            a2 = fmaf(kv.z, qv.z, a2);
            a3 = fmaf(kv.w, qv.w, a3);
        }
        float p = (a0 + a1) + (a2 + a3);
        p += __shfl_xor(p, 1, 64);
        p += __shfl_xor(p, 2, 64);
        if (j == 0) sc_lds[l] = p;       // padding -> dummy slot Lseq
    }
    __syncthreads();

    // ---- Phase 2: gated masked softmax over all 200 positions ----
    float logit = -INFINITY;
    if (tid < Lseq) {
        const int   dt = dts[b * Lseq + tid];
        const float g  = (dt == 0) ? 0.f : gate[dt];   // padding_idx=0
        logit = m ? (sc_lds[tid] * g * inv_tau) : -INFINITY;
    }
    float v = logit;
    #pragma unroll
    for (int off = 32; off > 0; off >>= 1)
        v = fmaxf(v, __shfl_xor(v, off, 64));
    if (lane == 0) redmax[wave] = v;
    __syncthreads();
    const float mx = fmaxf(fmaxf(redmax[0], redmax[1]), fmaxf(redmax[2], redmax[3]));

    const float e_ = (tid < Lseq) ? expf(logit - mx) : 0.f;
    v = e_;
    #pragma unroll
    for (int off = 32; off > 0; off >>= 1)
        v += __shfl_xor(v, off, 64);
    if (lane == 0) redsum[wave] = v;
    __syncthreads();
    const float inv_s = 1.0f / (redsum[0] + redsum[1] + redsum[2] + redsum[3]);

    if (tid < Lseq) {
        const float a = e_ * inv_s;      // masked: e_=0 -> a=0
        out_attn[b * Lseq + tid] = a;
        if (m) cattn_lds[cidx] = a;      // compacted attn for phase 3
    }
    __syncthreads();

    // ---- Phase 3: 8-deep pipelined coalesced gather over compacted list ----
    float acc = 0.f;
    for (int e0 = wave; e0 < cntp; e0 += 32) {      // cntp % 32 == 0
        int   rw[8];
        float aw[8], kv[8];
        #pragma unroll
        for (int k = 0; k < 8; ++k) rw[k] = crow_lds[e0 + 4 * k];   // broadcast
        #pragma unroll
        for (int k = 0; k < 8; ++k) aw[k] = cattn_lds[e0 + 4 * k];  // broadcast
        #pragma unroll
        for (int k = 0; k < 8; ++k) kv[k] = emb[(size_t)rw[k] * Dim + lane];
        #pragma unroll
        for (int k = 0; k < 8; ++k) acc = fmaf(aw[k], kv[k], acc);
    }
    part[wave][lane] = acc;
    __syncthreads();
    if (wave == 0)
        out_u[b * Dim + lane] = (part[0][lane] + part[1][lane])
                              + (part[2][lane] + part[3][lane]);
}

extern "C" void kernel_launch(void* const* d_in, const int* in_sizes, int n_in,
                              void* d_out, int out_size, void* d_ws, size_t ws_size,
                              hipStream_t stream) {
    const int*   items  = (const int*)  d_in[0];  // [B,L]
    const int*   dts    = (const int*)  d_in[1];  // [B,L]
    const int*   mask   = (const int*)  d_in[2];  // [B,L]
    const int*   cand   = (const int*)  d_in[3];  // [B]
    const float* emb    = (const float*)d_in[4];  // [VOCAB,64]
    const float* gate   = (const float*)d_in[5];  // [128,1]
    const float* rawtau = (const float*)d_in[6];  // [1]

    float* out_u    = (float*)d_out;                       // B*64
    float* out_attn = out_u + Bsz * Dim;                   // B*200
    float* out_tau  = out_attn + Bsz * Lseq;               // 1

    cac_kernel<<<Bsz, 256, 0, stream>>>(items, dts, mask, cand, emb, gate, rawtau,
                                        out_u, out_attn, out_tau);
}

// Round 11
// 100.797 us; speedup vs baseline: 2.9696x; 1.1076x over previous
//
#include <hip/hip_runtime.h>
#include <math.h>

// CandidateAwareClock: per row b
//   q = emb[cand[b]]; k_l = emb[items[b,l]]
//   logits_l = dot(k_l,q) * gate[dts[b,l]] / tau   (gate row 0 == 0)
//   masked softmax over l -> attn; u = sum_l attn_l * k_l
//   tau = softplus(raw_tau) + 1e-6
// Outputs concatenated: u [B*64], attn [B*200], tau [1]
//
// R9 (2nd resubmit after infra timeouts): single-pass online-softmax
// (flash-style), ONE WAVE PER ROW.
//  - one gather pass: k rows loaded once; acc[16]/lane accumulates w*k with
//    defer-rescale (rescale only when group max > running max; wave-uniform)
//  - zero __syncthreads: in-wave ballot compaction, shuffle reduces,
//    per-wave LDS lists (DS ops are in-order within a wave)
//  - attn recomputed exactly at end: exp(logit - m_final) / s
//  - 4 lanes per entry (lane=4r+j): 64B/lane aligned chunks, 2-shuffle sim
//    reduce; 16 entries per wave-iteration
// Grid 1024 x 4 waves = 4096 waves (grid-limited ~16 waves/CU) ->
// __launch_bounds__(256,2): VGPR up to 128 is free.

constexpr int Bsz  = 4096;
constexpr int Lseq = 200;
constexpr int Dim  = 64;
constexpr int WPB  = 4;     // waves per block; one batch row per wave

__global__ __launch_bounds__(256, 2)
void cac_kernel(const int* __restrict__ items,
                const int* __restrict__ dts,
                const int* __restrict__ mask,
                const int* __restrict__ cand,
                const float* __restrict__ emb,
                const float* __restrict__ gate,
                const float* __restrict__ rawtau,
                float* __restrict__ out_u,
                float* __restrict__ out_attn,
                float* __restrict__ out_tau)
{
    __shared__ int   cpos[WPB][Lseq];    // compacted -> original position
    __shared__ int   crow[WPB][Lseq];    // compacted -> item row
    __shared__ float cgate[WPB][Lseq];   // compacted -> gate value
    __shared__ float clog[WPB][Lseq];    // compacted -> logit (for attn out)

    const int tid  = threadIdx.x;
    const int wv   = tid >> 6;
    const int lane = tid & 63;
    const int b    = blockIdx.x * WPB + wv;

    // tau
    const float raw = rawtau[0];
    const float sp  = (raw > 20.f) ? raw : log1pf(expf(raw));
    const float tau = sp + 1e-6f;
    const float inv_tau = 1.0f / tau;
    if (b == 0 && tid == 0) out_tau[0] = tau;

    // per-lane loads for 4 position chunks (p = 64k + lane)
    int rowk[4], mk[4];
    float gk[4];
    #pragma unroll
    for (int k = 0; k < 4; ++k) {
        const int  p  = k * 64 + lane;
        const bool in = (p < Lseq);
        rowk[k] = in ? items[(size_t)b * Lseq + p] : 0;
        mk[k]   = in ? mask[(size_t)b * Lseq + p] : 0;
        const int dt = in ? dts[(size_t)b * Lseq + p] : 0;
        gk[k] = (dt == 0) ? 0.f : gate[dt];          // padding_idx=0; 512B table in L1
    }

    // ---- in-wave ballot compaction (no barriers) ----
    unsigned long long bals[4];
    int offs[5];
    offs[0] = 0;
    #pragma unroll
    for (int k = 0; k < 4; ++k) {
        bals[k] = __ballot(mk[k] != 0);
        offs[k + 1] = offs[k] + __popcll(bals[k]);
    }
    const int cnt = offs[4];                         // >=1 (mask[:,0]=True)
    const unsigned long long ltmask = (1ull << lane) - 1ull;
    #pragma unroll
    for (int k = 0; k < 4; ++k) {
        if (mk[k]) {
            const int idx = offs[k] + __popcll(bals[k] & ltmask);
            cpos[wv][idx]  = k * 64 + lane;
            crow[wv][idx]  = rowk[k];
            cgate[wv][idx] = gk[k];
        }
    }

    // q fragment in registers: lane (r,j) holds q dims {16i+4j+t}
    const int r = lane >> 2;
    const int j = lane & 3;
    const float4* qrow = (const float4*)(emb + (size_t)cand[b] * Dim);
    float4 qv[4];
    #pragma unroll
    for (int i = 0; i < 4; ++i) qv[i] = qrow[i * 4 + j];

    // ---- single-pass gather + online softmax + weighted accumulate ----
    float acc[16];
    #pragma unroll
    for (int i = 0; i < 16; ++i) acc[i] = 0.f;
    float m = -INFINITY, s_l = 0.f;

    const int ngrp = (cnt + 15) >> 4;
    for (int g = 0; g < ngrp; ++g) {
        const int  e     = g * 16 + r;
        const bool valid = (e < cnt);
        const int  ec    = valid ? e : (cnt - 1);
        const int  row   = crow[wv][ec];             // 4-lane same-addr broadcast
        const float cg   = cgate[wv][ec];
        const float4* kp = (const float4*)(emb + (size_t)row * Dim);
        float4 kv[4];
        #pragma unroll
        for (int i = 0; i < 4; ++i) kv[i] = kp[i * 4 + j];   // lane's 64B line

        float p = 0.f;
        #pragma unroll
        for (int i = 0; i < 4; ++i) {
            p = fmaf(kv[i].x, qv[i].x, p);
            p = fmaf(kv[i].y, qv[i].y, p);
            p = fmaf(kv[i].z, qv[i].z, p);
            p = fmaf(kv[i].w, qv[i].w, p);
        }
        p += __shfl_xor(p, 1, 64);                   // sum over j (4 lanes)
        p += __shfl_xor(p, 2, 64);

        const float logit = p * cg * inv_tau;
        const float leff  = valid ? logit : -INFINITY;

        float gm = leff;                             // max over the 16 entries
        #pragma unroll
        for (int off = 4; off < 64; off <<= 1)
            gm = fmaxf(gm, __shfl_xor(gm, off, 64));

        if (gm > m) {                                // wave-uniform, rare later
            const float scale = __expf(m - gm);      // m=-inf first iter -> 0
            s_l *= scale;
            #pragma unroll
            for (int i = 0; i < 16; ++i) acc[i] *= scale;
            m = gm;
        }

        const float wgt = __expf(leff - m);          // invalid -> exp(-inf)=0
        if (valid && j == 0) clog[wv][e] = logit;
        if (j == 0) s_l += wgt;                      // count each entry once
        #pragma unroll
        for (int i = 0; i < 4; ++i) {
            acc[4 * i + 0] = fmaf(wgt, kv[i].x, acc[4 * i + 0]);
            acc[4 * i + 1] = fmaf(wgt, kv[i].y, acc[4 * i + 1]);
            acc[4 * i + 2] = fmaf(wgt, kv[i].z, acc[4 * i + 2]);
            acc[4 * i + 3] = fmaf(wgt, kv[i].w, acc[4 * i + 3]);
        }
    }

    // ---- reduce acc across the 16 r-groups (same j = same dims) ----
    #pragma unroll
    for (int off = 4; off < 64; off <<= 1) {
        #pragma unroll
        for (int i = 0; i < 16; ++i) acc[i] += __shfl_xor(acc[i], off, 64);
    }
    float s = s_l;                                   // nonzero only at j==0 lanes
    #pragma unroll
    for (int off = 1; off < 64; off <<= 1) s += __shfl_xor(s, off, 64);
    const float inv_s = 1.0f / s;

    // u write: lanes 0..3 (r==0, j=lane) each own 16 dims = 4 float4s
    if (r == 0) {
        float4* up = (float4*)(out_u + (size_t)b * Dim);
        #pragma unroll
        for (int i = 0; i < 4; ++i) {
            float4 o;
            o.x = acc[4 * i + 0] * inv_s;
            o.y = acc[4 * i + 1] * inv_s;
            o.z = acc[4 * i + 2] * inv_s;
            o.w = acc[4 * i + 3] * inv_s;
            up[i * 4 + j] = o;                       // dims 16i+4j..+3
        }
    }

    // attn: masked positions -> 0 (each position has exactly one writer)
    #pragma unroll
    for (int k = 0; k < 4; ++k) {
        const int p = k * 64 + lane;
        if (p < Lseq && !mk[k]) out_attn[(size_t)b * Lseq + p] = 0.f;
    }
    for (int e = lane; e < cnt; e += 64) {
        const float a = __expf(clog[wv][e] - m) * inv_s;
        out_attn[(size_t)b * Lseq + cpos[wv][e]] = a;
    }
}

extern "C" void kernel_launch(void* const* d_in, const int* in_sizes, int n_in,
                              void* d_out, int out_size, void* d_ws, size_t ws_size,
                              hipStream_t stream) {
    const int*   items  = (const int*)  d_in[0];  // [B,L]
    const int*   dts    = (const int*)  d_in[1];  // [B,L]
    const int*   mask   = (const int*)  d_in[2];  // [B,L]
    const int*   cand   = (const int*)  d_in[3];  // [B]
    const float* emb    = (const float*)d_in[4];  // [VOCAB,64]
    const float* gate   = (const float*)d_in[5];  // [128,1]
    const float* rawtau = (const float*)d_in[6];  // [1]

    float* out_u    = (float*)d_out;                       // B*64
    float* out_attn = out_u + Bsz * Dim;                   // B*200
    float* out_tau  = out_attn + Bsz * Lseq;               // 1

    cac_kernel<<<Bsz / WPB, 256, 0, stream>>>(items, dts, mask, cand, emb, gate,
                                              rawtau, out_u, out_attn, out_tau);
}